// Round 1
// baseline (5470.903 us; speedup 1.0000x reference)
//
#include <hip/hip_runtime.h>
#include <stdint.h>

#define N_SITES 131072
#define CIN0 256
#define HID 512
#define KTAPS 9
#define NLAYERS 8

typedef __bf16 bf16x8 __attribute__((ext_vector_type(8)));
typedef float f32x4 __attribute__((ext_vector_type(4)));

__device__ __forceinline__ unsigned short f2bf(float f) {
    union { float f; unsigned u; } v; v.f = f;
    return (unsigned short)((v.u + 0x7fffu + ((v.u >> 16) & 1u)) >> 16);
}

// ---------------- prep kernels ----------------

// features fp32 [N,256] -> bf16 [N,256]; 8 elems/thread
__global__ void cvt_features_kernel(const float* __restrict__ in, unsigned short* __restrict__ out) {
    int t = blockIdx.x * 256 + threadIdx.x;
    const float4* p = (const float4*)in + 2 * (size_t)t;
    float4 a = p[0], b = p[1];
    uint4 o;
    o.x = f2bf(a.x) | ((unsigned)f2bf(a.y) << 16);
    o.y = f2bf(a.z) | ((unsigned)f2bf(a.w) << 16);
    o.z = f2bf(b.x) | ((unsigned)f2bf(b.y) << 16);
    o.w = f2bf(b.z) | ((unsigned)f2bf(b.w) << 16);
    ((uint4*)out)[t] = o;
}

// zero row at index N for both stride-256 (layer 0) and stride-512 layouts
__global__ void zero_rows_kernel(unsigned short* __restrict__ x) {
    int t = threadIdx.x; // 256 threads
    x[(size_t)N_SITES * 256 + t] = 0;
    x[(size_t)N_SITES * 512 + t] = 0;
    x[(size_t)N_SITES * 512 + 256 + t] = 0;
}

// w fp32 [T][cin][512] -> bf16 [T][512][cin]  (per-tap transpose, LDS tiled)
__global__ void transpose_w_kernel(const float* __restrict__ in, unsigned short* __restrict__ out, int cin) {
    __shared__ float tile[32][33];
    int m = blockIdx.z;
    int nb = blockIdx.x * 32;   // over HID=512 (input inner dim)
    int cb = blockIdx.y * 32;   // over cin
    int tx = threadIdx.x, ty = threadIdx.y;
    const float* src = in + (size_t)m * cin * HID;
    unsigned short* dst = out + (size_t)m * HID * cin;
#pragma unroll
    for (int j = 0; j < 4; ++j) {
        int r = ty + 8 * j;
        tile[r][tx] = src[(size_t)(cb + r) * HID + nb + tx];
    }
    __syncthreads();
#pragma unroll
    for (int j = 0; j < 4; ++j) {
        int r = ty + 8 * j;
        dst[(size_t)(nb + r) * cin + cb + tx] = f2bf(tile[tx][r]);
    }
}

// ---------------- gathered GEMM ----------------

__device__ __forceinline__ void async16(const void* g, void* l) {
    __builtin_amdgcn_global_load_lds(
        (__attribute__((address_space(1))) unsigned int*)(g),
        (__attribute__((address_space(3))) unsigned int*)(l),
        16, 0, 0);
}

// out[rowbase+m][colbase+n] = sum_tap sum_k x[nbr[m,tap]][k] * wt[tap][n][k]
// x: bf16 [N+1][cin], wt: bf16 [9][512][cin], out: fp32 [N][512]
__global__ __launch_bounds__(256) void subm_gemm_kernel(
    const unsigned short* __restrict__ x,
    const int* __restrict__ nbr,
    const unsigned short* __restrict__ wt,
    float* __restrict__ out,
    int cin)
{
    // LDS: 16B slots. slot p holds (row = p>>3, chunk = (p&7) ^ (row&7)) of the
    // current 128x64 bf16 tile. Staging is lane-contiguous (global_load_lds
    // requirement); fragment ds_read_b128 lands banks 2-way only (free).
    __shared__ uint4 As[1024];
    __shared__ uint4 Bs[1024];

    const int tid = threadIdx.x;
    const int lane = tid & 63;
    const int wave = tid >> 6;
    const int rowbase = (int)(blockIdx.x >> 2) * 128;
    const int colbase = (int)(blockIdx.x & 3) * 128;
    const int wm = (wave >> 1) * 64;
    const int wn = (wave & 1) * 64;

    const int r0 = tid >> 3;                  // 0..31: row (or col) this thread stages
    const int cs = tid & 7;                   // chunk slot within row
    const int chunk = cs ^ (r0 & 7);          // global 16B-chunk this thread fetches
    const int ldsbase = tid & ~63;            // wave-uniform slot base
    const int kiters = cin >> 6;

    const f32x4 zero4 = {0.f, 0.f, 0.f, 0.f};
    f32x4 acc[4][4];
#pragma unroll
    for (int i = 0; i < 4; ++i)
#pragma unroll
        for (int j = 0; j < 4; ++j)
            acc[i][j] = zero4;

    for (int tap = 0; tap < KTAPS; ++tap) {
        const unsigned short* arow[4];
#pragma unroll
        for (int i = 0; i < 4; ++i) {
            int idx = nbr[(size_t)(rowbase + r0 + 32 * i) * KTAPS + tap];
            if (idx < 0) idx = N_SITES;       // zero row
            arow[i] = x + (size_t)idx * cin + chunk * 8;
        }
        const unsigned short* wbase = wt + ((size_t)tap * HID + colbase) * cin + chunk * 8;
        const unsigned short* brow[4];
#pragma unroll
        for (int i = 0; i < 4; ++i)
            brow[i] = wbase + (size_t)(r0 + 32 * i) * cin;

        for (int kk = 0; kk < kiters; ++kk) {
            const int ko = kk * 64;
            __syncthreads();                  // LDS reuse guard
#pragma unroll
            for (int i = 0; i < 4; ++i) {
                async16(arow[i] + ko, &As[ldsbase + 256 * i]);
                async16(brow[i] + ko, &Bs[ldsbase + 256 * i]);
            }
            __syncthreads();                  // compiler drains vmcnt before barrier

#pragma unroll
            for (int ks = 0; ks < 2; ++ks) {
                bf16x8 af[4], bfr[4];
#pragma unroll
                for (int f = 0; f < 4; ++f) {
                    int rl = wm + f * 16 + (lane & 15);
                    int ch = ks * 4 + (lane >> 4);
                    af[f]  = __builtin_bit_cast(bf16x8, As[rl * 8 + (ch ^ (rl & 7))]);
                    int cl = wn + f * 16 + (lane & 15);
                    bfr[f] = __builtin_bit_cast(bf16x8, Bs[cl * 8 + (ch ^ (cl & 7))]);
                }
#pragma unroll
                for (int i = 0; i < 4; ++i)
#pragma unroll
                    for (int j = 0; j < 4; ++j)
                        acc[i][j] = __builtin_amdgcn_mfma_f32_16x16x32_bf16(af[i], bfr[j], acc[i][j], 0, 0, 0);
            }
        }
    }

    // C/D: col = lane&15, row = (lane>>4)*4 + reg (m89/m91-verified)
#pragma unroll
    for (int i = 0; i < 4; ++i) {
        int grow = rowbase + wm + i * 16 + (lane >> 4) * 4;
#pragma unroll
        for (int j = 0; j < 4; ++j) {
            int gcol = colbase + wn + j * 16 + (lane & 15);
#pragma unroll
            for (int r = 0; r < 4; ++r)
                out[(size_t)(grow + r) * HID + gcol] = acc[i][j][r];
        }
    }
}

// ---------------- fused GroupNorm + ReLU ----------------
// one wave per row; lane holds ch [lane*4, lane*4+4) and [256+lane*4, ...+4).
// group = 16 channels = 4 aligned lanes -> shfl_xor(1), shfl_xor(2).
__global__ void gn_relu_kernel(const float* __restrict__ conv,
                               const float* __restrict__ gamma,
                               const float* __restrict__ beta,
                               unsigned short* __restrict__ bf_out,
                               float* __restrict__ f_out,
                               int write_bf16)
{
    int row = blockIdx.x * 4 + (threadIdx.x >> 6);
    int lane = threadIdx.x & 63;
    const float4* src = (const float4*)(conv + (size_t)row * HID);
    float4 a = src[lane];
    float4 b = src[64 + lane];
    float sa = a.x + a.y + a.z + a.w;
    float qa = a.x * a.x + a.y * a.y + a.z * a.z + a.w * a.w;
    float sb = b.x + b.y + b.z + b.w;
    float qb = b.x * b.x + b.y * b.y + b.z * b.z + b.w * b.w;
    sa += __shfl_xor(sa, 1); qa += __shfl_xor(qa, 1);
    sa += __shfl_xor(sa, 2); qa += __shfl_xor(qa, 2);
    sb += __shfl_xor(sb, 1); qb += __shfl_xor(qb, 1);
    sb += __shfl_xor(sb, 2); qb += __shfl_xor(qb, 2);
    float ma = sa * 0.0625f;
    float ra = rsqrtf(qa * 0.0625f - ma * ma + 1e-5f);
    float mb = sb * 0.0625f;
    float rb = rsqrtf(qb * 0.0625f - mb * mb + 1e-5f);

    const float4* g4 = (const float4*)gamma;
    const float4* b4 = (const float4*)beta;
    float4 ga = g4[lane], gb = g4[64 + lane];
    float4 ba = b4[lane], bb = b4[64 + lane];
    float4 ya, yb;
    ya.x = fmaxf(0.f, (a.x - ma) * ra * ga.x + ba.x);
    ya.y = fmaxf(0.f, (a.y - ma) * ra * ga.y + ba.y);
    ya.z = fmaxf(0.f, (a.z - ma) * ra * ga.z + ba.z);
    ya.w = fmaxf(0.f, (a.w - ma) * ra * ga.w + ba.w);
    yb.x = fmaxf(0.f, (b.x - mb) * rb * gb.x + bb.x);
    yb.y = fmaxf(0.f, (b.y - mb) * rb * gb.y + bb.y);
    yb.z = fmaxf(0.f, (b.z - mb) * rb * gb.z + bb.z);
    yb.w = fmaxf(0.f, (b.w - mb) * rb * gb.w + bb.w);

    if (write_bf16) {
        uint2* dst = (uint2*)(bf_out + (size_t)row * HID);
        uint2 pa, pb;
        pa.x = f2bf(ya.x) | ((unsigned)f2bf(ya.y) << 16);
        pa.y = f2bf(ya.z) | ((unsigned)f2bf(ya.w) << 16);
        pb.x = f2bf(yb.x) | ((unsigned)f2bf(yb.y) << 16);
        pb.y = f2bf(yb.z) | ((unsigned)f2bf(yb.w) << 16);
        dst[lane] = pa;
        dst[64 + lane] = pb;
    } else {
        float4* dst = (float4*)(f_out + (size_t)row * HID);
        dst[lane] = ya;
        dst[64 + lane] = yb;
    }
}

// ---------------- launch ----------------

extern "C" void kernel_launch(void* const* d_in, const int* in_sizes, int n_in,
                              void* d_out, int out_size, void* d_ws, size_t ws_size,
                              hipStream_t stream) {
    const float* features = (const float*)d_in[0];
    const int*   nbr      = (const int*)d_in[1];
    const float* w0       = (const float*)d_in[2];
    const float* w_rest   = (const float*)d_in[3];
    const float* gamma    = (const float*)d_in[4];
    const float* beta     = (const float*)d_in[5];
    float* out = (float*)d_out;

    // workspace: x bf16 [(N+1)*512] | w0_t bf16 [9*512*256] | w_rest_t bf16 [63*512*512]
    unsigned short* xbuf = (unsigned short*)d_ws;
    size_t xbytes = (size_t)(N_SITES + 1) * HID * sizeof(unsigned short);
    unsigned short* w0t = (unsigned short*)((char*)d_ws + xbytes);
    size_t w0t_bytes = (size_t)KTAPS * HID * CIN0 * sizeof(unsigned short);
    unsigned short* wrt = (unsigned short*)((char*)d_ws + xbytes + w0t_bytes);

    cvt_features_kernel<<<N_SITES * CIN0 / (256 * 8), 256, 0, stream>>>(features, xbuf);
    zero_rows_kernel<<<1, 256, 0, stream>>>(xbuf);
    transpose_w_kernel<<<dim3(HID / 32, CIN0 / 32, KTAPS), dim3(32, 8), 0, stream>>>(w0, w0t, CIN0);
    transpose_w_kernel<<<dim3(HID / 32, HID / 32, (NLAYERS - 1) * KTAPS), dim3(32, 8), 0, stream>>>(w_rest, wrt, HID);

    for (int l = 0; l < NLAYERS; ++l) {
        const unsigned short* wt = (l == 0) ? w0t : wrt + (size_t)(l - 1) * KTAPS * HID * HID;
        int cin = (l == 0) ? CIN0 : HID;
        subm_gemm_kernel<<<(N_SITES / 128) * 4, 256, 0, stream>>>(xbuf, nbr, wt, out, cin);
        gn_relu_kernel<<<N_SITES / 4, 256, 0, stream>>>(out, gamma + (size_t)l * HID, beta + (size_t)l * HID,
                                                        xbuf, out, (l < NLAYERS - 1) ? 1 : 0);
    }
}

// Round 2
// 5286.787 us; speedup vs baseline: 1.0348x; 1.0348x over previous
//
#include <hip/hip_runtime.h>
#include <stdint.h>

#define N_SITES 131072
#define CIN0 256
#define HID 512
#define KTAPS 9
#define NLAYERS 8

typedef __bf16 bf16x8 __attribute__((ext_vector_type(8)));
typedef float f32x4 __attribute__((ext_vector_type(4)));

__device__ __forceinline__ unsigned short f2bf(float f) {
    union { float f; unsigned u; } v; v.f = f;
    return (unsigned short)((v.u + 0x7fffu + ((v.u >> 16) & 1u)) >> 16);
}

// ---------------- prep kernels ----------------

__global__ void cvt_features_kernel(const float* __restrict__ in, unsigned short* __restrict__ out) {
    int t = blockIdx.x * 256 + threadIdx.x;
    const float4* p = (const float4*)in + 2 * (size_t)t;
    float4 a = p[0], b = p[1];
    uint4 o;
    o.x = f2bf(a.x) | ((unsigned)f2bf(a.y) << 16);
    o.y = f2bf(a.z) | ((unsigned)f2bf(a.w) << 16);
    o.z = f2bf(b.x) | ((unsigned)f2bf(b.y) << 16);
    o.w = f2bf(b.z) | ((unsigned)f2bf(b.w) << 16);
    ((uint4*)out)[t] = o;
}

__global__ void zero_rows_kernel(unsigned short* __restrict__ x) {
    int t = threadIdx.x; // 256 threads
    x[(size_t)N_SITES * 256 + t] = 0;
    x[(size_t)N_SITES * 512 + t] = 0;
    x[(size_t)N_SITES * 512 + 256 + t] = 0;
}

// w fp32 [T][cin][512] -> bf16 [T][512][cin]
__global__ void transpose_w_kernel(const float* __restrict__ in, unsigned short* __restrict__ out, int cin) {
    __shared__ float tile[32][33];
    int m = blockIdx.z;
    int nb = blockIdx.x * 32;
    int cb = blockIdx.y * 32;
    int tx = threadIdx.x, ty = threadIdx.y;
    const float* src = in + (size_t)m * cin * HID;
    unsigned short* dst = out + (size_t)m * HID * cin;
#pragma unroll
    for (int j = 0; j < 4; ++j) {
        int r = ty + 8 * j;
        tile[r][tx] = src[(size_t)(cb + r) * HID + nb + tx];
    }
    __syncthreads();
#pragma unroll
    for (int j = 0; j < 4; ++j) {
        int r = ty + 8 * j;
        dst[(size_t)(nb + r) * cin + cb + tx] = f2bf(tile[tx][r]);
    }
}

// ---------------- gathered GEMM ----------------

__device__ __forceinline__ void async16(const void* g, void* l) {
    __builtin_amdgcn_global_load_lds(
        (__attribute__((address_space(1))) unsigned int*)(g),
        (__attribute__((address_space(3))) unsigned int*)(l),
        16, 0, 0);
}

// out[rowbase+m][colbase+n] = sum_tap sum_k x[nbr[m,tap]][k] * wt[tap][n][k]
__global__ __launch_bounds__(256, 4) void subm_gemm_kernel(
    const unsigned short* __restrict__ x,
    const int* __restrict__ nbr,
    const unsigned short* __restrict__ wt,
    float* __restrict__ out,
    int cin)
{
    __shared__ uint4 As[1024];
    __shared__ uint4 Bs[1024];

    const int tid = threadIdx.x;
    const int lane = tid & 63;
    const int wave = tid >> 6;

    // XCD/L2-aware swizzle. Dispatch round-robins blocks across 8 XCDs
    // (xcd = blockIdx % 8). Give each XCD a FIXED col-tile (B slice 1.18 MB
    // stays L2-resident) and a CONTIGUOUS rb sweep (gather windows of
    // consecutive rb overlap ~89% -> A tiles hit L2, not L3/HBM).
    const int b = (int)blockIdx.x;
    const int xcd = b & 7;
    const int slot = b >> 3;                  // 0..511
    const int colbase = (xcd & 3) * 128;
    const int rowbase = ((xcd >> 2) * 512 + slot) * 128;

    const int wm = (wave >> 1) * 64;
    const int wn = (wave & 1) * 64;

    const int r0 = tid >> 3;                  // 0..31
    const int cs = tid & 7;
    const int chunk = cs ^ (r0 & 7);
    const int ldsbase = tid & ~63;
    const int kiters = cin >> 6;

    const f32x4 zero4 = {0.f, 0.f, 0.f, 0.f};
    f32x4 acc[4][4];
#pragma unroll
    for (int i = 0; i < 4; ++i)
#pragma unroll
        for (int j = 0; j < 4; ++j)
            acc[i][j] = zero4;

    for (int tap = 0; tap < KTAPS; ++tap) {
        const unsigned short* arow[4];
#pragma unroll
        for (int i = 0; i < 4; ++i) {
            int idx = nbr[(size_t)(rowbase + r0 + 32 * i) * KTAPS + tap];
            if (idx < 0) idx = N_SITES;
            arow[i] = x + (size_t)idx * cin + chunk * 8;
        }
        const unsigned short* wbase = wt + ((size_t)tap * HID + colbase) * cin + chunk * 8;
        const unsigned short* brow[4];
#pragma unroll
        for (int i = 0; i < 4; ++i)
            brow[i] = wbase + (size_t)(r0 + 32 * i) * cin;

        for (int kk = 0; kk < kiters; ++kk) {
            const int ko = kk * 64;
            __syncthreads();
#pragma unroll
            for (int i = 0; i < 4; ++i) {
                async16(arow[i] + ko, &As[ldsbase + 256 * i]);
                async16(brow[i] + ko, &Bs[ldsbase + 256 * i]);
            }
            __syncthreads();

#pragma unroll
            for (int ks = 0; ks < 2; ++ks) {
                bf16x8 af[4], bfr[4];
#pragma unroll
                for (int f = 0; f < 4; ++f) {
                    int rl = wm + f * 16 + (lane & 15);
                    int ch = ks * 4 + (lane >> 4);
                    af[f]  = __builtin_bit_cast(bf16x8, As[rl * 8 + (ch ^ (rl & 7))]);
                    int cl = wn + f * 16 + (lane & 15);
                    bfr[f] = __builtin_bit_cast(bf16x8, Bs[cl * 8 + (ch ^ (cl & 7))]);
                }
#pragma unroll
                for (int i = 0; i < 4; ++i)
#pragma unroll
                    for (int j = 0; j < 4; ++j)
                        acc[i][j] = __builtin_amdgcn_mfma_f32_16x16x32_bf16(af[i], bfr[j], acc[i][j], 0, 0, 0);
            }
        }
    }

    // C/D: col = lane&15, row = (lane>>4)*4 + reg
#pragma unroll
    for (int i = 0; i < 4; ++i) {
        int grow = rowbase + wm + i * 16 + (lane >> 4) * 4;
#pragma unroll
        for (int j = 0; j < 4; ++j) {
            int gcol = colbase + wn + j * 16 + (lane & 15);
#pragma unroll
            for (int r = 0; r < 4; ++r)
                out[(size_t)(grow + r) * HID + gcol] = acc[i][j][r];
        }
    }
}

// ---------------- fused GroupNorm + ReLU ----------------

__global__ void gn_relu_kernel(const float* __restrict__ conv,
                               const float* __restrict__ gamma,
                               const float* __restrict__ beta,
                               unsigned short* __restrict__ bf_out,
                               float* __restrict__ f_out,
                               int write_bf16)
{
    int row = blockIdx.x * 4 + (threadIdx.x >> 6);
    int lane = threadIdx.x & 63;
    const float4* src = (const float4*)(conv + (size_t)row * HID);
    float4 a = src[lane];
    float4 b = src[64 + lane];
    float sa = a.x + a.y + a.z + a.w;
    float qa = a.x * a.x + a.y * a.y + a.z * a.z + a.w * a.w;
    float sb = b.x + b.y + b.z + b.w;
    float qb = b.x * b.x + b.y * b.y + b.z * b.z + b.w * b.w;
    sa += __shfl_xor(sa, 1); qa += __shfl_xor(qa, 1);
    sa += __shfl_xor(sa, 2); qa += __shfl_xor(qa, 2);
    sb += __shfl_xor(sb, 1); qb += __shfl_xor(qb, 1);
    sb += __shfl_xor(sb, 2); qb += __shfl_xor(qb, 2);
    float ma = sa * 0.0625f;
    float ra = rsqrtf(qa * 0.0625f - ma * ma + 1e-5f);
    float mb = sb * 0.0625f;
    float rb = rsqrtf(qb * 0.0625f - mb * mb + 1e-5f);

    const float4* g4 = (const float4*)gamma;
    const float4* b4 = (const float4*)beta;
    float4 ga = g4[lane], gb = g4[64 + lane];
    float4 ba = b4[lane], bb = b4[64 + lane];
    float4 ya, yb;
    ya.x = fmaxf(0.f, (a.x - ma) * ra * ga.x + ba.x);
    ya.y = fmaxf(0.f, (a.y - ma) * ra * ga.y + ba.y);
    ya.z = fmaxf(0.f, (a.z - ma) * ra * ga.z + ba.z);
    ya.w = fmaxf(0.f, (a.w - ma) * ra * ga.w + ba.w);
    yb.x = fmaxf(0.f, (b.x - mb) * rb * gb.x + bb.x);
    yb.y = fmaxf(0.f, (b.y - mb) * rb * gb.y + bb.y);
    yb.z = fmaxf(0.f, (b.z - mb) * rb * gb.z + bb.z);
    yb.w = fmaxf(0.f, (b.w - mb) * rb * gb.w + bb.w);

    if (write_bf16) {
        uint2* dst = (uint2*)(bf_out + (size_t)row * HID);
        uint2 pa, pb;
        pa.x = f2bf(ya.x) | ((unsigned)f2bf(ya.y) << 16);
        pa.y = f2bf(ya.z) | ((unsigned)f2bf(ya.w) << 16);
        pb.x = f2bf(yb.x) | ((unsigned)f2bf(yb.y) << 16);
        pb.y = f2bf(yb.z) | ((unsigned)f2bf(yb.w) << 16);
        dst[lane] = pa;
        dst[64 + lane] = pb;
    } else {
        float4* dst = (float4*)(f_out + (size_t)row * HID);
        dst[lane] = ya;
        dst[64 + lane] = yb;
    }
}

// ---------------- launch ----------------

extern "C" void kernel_launch(void* const* d_in, const int* in_sizes, int n_in,
                              void* d_out, int out_size, void* d_ws, size_t ws_size,
                              hipStream_t stream) {
    const float* features = (const float*)d_in[0];
    const int*   nbr      = (const int*)d_in[1];
    const float* w0       = (const float*)d_in[2];
    const float* w_rest   = (const float*)d_in[3];
    const float* gamma    = (const float*)d_in[4];
    const float* beta     = (const float*)d_in[5];
    float* out = (float*)d_out;

    unsigned short* xbuf = (unsigned short*)d_ws;
    size_t xbytes = (size_t)(N_SITES + 1) * HID * sizeof(unsigned short);
    unsigned short* w0t = (unsigned short*)((char*)d_ws + xbytes);
    size_t w0t_bytes = (size_t)KTAPS * HID * CIN0 * sizeof(unsigned short);
    unsigned short* wrt = (unsigned short*)((char*)d_ws + xbytes + w0t_bytes);

    cvt_features_kernel<<<N_SITES * CIN0 / (256 * 8), 256, 0, stream>>>(features, xbuf);
    zero_rows_kernel<<<1, 256, 0, stream>>>(xbuf);
    transpose_w_kernel<<<dim3(HID / 32, CIN0 / 32, KTAPS), dim3(32, 8), 0, stream>>>(w0, w0t, CIN0);
    transpose_w_kernel<<<dim3(HID / 32, HID / 32, (NLAYERS - 1) * KTAPS), dim3(32, 8), 0, stream>>>(w_rest, wrt, HID);

    for (int l = 0; l < NLAYERS; ++l) {
        const unsigned short* wt = (l == 0) ? w0t : wrt + (size_t)(l - 1) * KTAPS * HID * HID;
        int cin = (l == 0) ? CIN0 : HID;
        subm_gemm_kernel<<<(N_SITES / 128) * 4, 256, 0, stream>>>(xbuf, nbr, wt, out, cin);
        gn_relu_kernel<<<N_SITES / 4, 256, 0, stream>>>(out, gamma + (size_t)l * HID, beta + (size_t)l * HID,
                                                        xbuf, out, (l < NLAYERS - 1) ? 1 : 0);
    }
}